// Round 4
// baseline (38.338 us; speedup 1.0000x reference)
//
#include <hip/hip_runtime.h>

typedef float  f32x4 __attribute__((ext_vector_type(4)));
typedef _Float16 h16x8 __attribute__((ext_vector_type(8)));
typedef _Float16 h16x2 __attribute__((ext_vector_type(2)));

#define LOG2E 1.4426950408889634f
#define ALPHA 0.2f

__device__ __forceinline__ float fexp2(float v) {
#if __has_builtin(__builtin_amdgcn_exp2f)
  return __builtin_amdgcn_exp2f(v);
#else
  return exp2f(v);
#endif
}

// ---------------- kernel 1: f1/f2 rows, pre-scaled by log2(e) ----------------
__global__ __launch_bounds__(256) void fkern(
    const float* __restrict__ emb, const float* __restrict__ W,
    const float* __restrict__ a, float* __restrict__ f1, float* __restrict__ f2)
{
  __shared__ float w1s[64], w2s[64];
  const int t = threadIdx.x;
  if (t < 128) {
    const int d = t & 63;
    const float* wrow = W + d * 64;
    const float* av = a + (t >> 6) * 64;
    float s = 0.f;
#pragma unroll
    for (int h = 0; h < 64; ++h) s = fmaf(wrow[h], av[h], s);
    if (t < 64) w1s[d] = s; else w2s[d] = s;
  }
  __syncthreads();
  const int R = blockIdx.x * 64 + (t >> 2);
  const int q = t & 3;
  const f32x4* er = (const f32x4*)(emb + (size_t)R * 64 + q * 16);
  float s1 = 0.f, s2 = 0.f;
#pragma unroll
  for (int r = 0; r < 4; ++r) {
    f32x4 v = er[r];
#pragma unroll
    for (int c = 0; c < 4; ++c) {
      s1 = fmaf(v[c], w1s[q * 16 + r * 4 + c], s1);
      s2 = fmaf(v[c], w2s[q * 16 + r * 4 + c], s2);
    }
  }
  s1 += __shfl_xor(s1, 1); s1 += __shfl_xor(s1, 2);
  s2 += __shfl_xor(s2, 1); s2 += __shfl_xor(s2, 2);
  if (q == 0) { f1[R] = s1 * LOG2E; f2[R] = s2 * LOG2E; }
}

// ---------------- kernel 2: fused softmax(P) @ [x_b | x_{b+32}] ----------------
// grid 256, 1024 threads (16 waves, 4/SIMD).  b = bid>>3, row-tile = (bid&7)*128.
// Wave = (wr 0..7, wc 0..1): rows brow+wr*16+{0..15}, cols wc*64 + nf*16+{0..15}.
// p = max(CA*E1[j], CB*E2[j]) — no exp in inner loop.  Z via ones-column MFMA.
// Xt swizzled: 8-halfword block k8 ^= (row&7) — conflict-free b128 reads.
__global__ __launch_bounds__(1024, 1) void attn_main(
    const float* __restrict__ x, const float* __restrict__ f1g,
    const float* __restrict__ f2g, float* __restrict__ out)
{
  __shared__ __attribute__((aligned(16))) _Float16 Xt[2][128 * 128]; // [row=n][k] swizzled
  __shared__ float e1s[1024], e2s[1024];
  __shared__ float red[16];

  const int t    = threadIdx.x;
  const int wid  = t >> 6;
  const int lane = t & 63;
  const int l15  = lane & 15;
  const int g    = lane >> 4;          // k-group (0..3)
  const int wc   = wid & 1;            // col half (0..1)
  const int wr   = wid >> 1;           // row block (0..7)
  const int b    = blockIdx.x >> 3;
  const int brow = (blockIdx.x & 7) * 128;

  float rv[16];  // staged global values for next chunk (static-indexed)

  auto stage_loads = [&](int kc) {
#pragma unroll
    for (int p = 0; p < 2; ++p) {
      const int pp = wid * 2 + p;
      const int h  = pp >> 4;
      const int j0 = (pp & 15) * 8;
      const float* base = x + (size_t)(b + 32 * h) * 65536
                            + (size_t)(kc * 128 + j0 + 2 * g) * 64 + l15;
#pragma unroll
      for (int i = 0; i < 4; ++i) {
        rv[p * 8 + i]     = base[i * 16];        // j even, d = l15+16i
        rv[p * 8 + 4 + i] = base[64 + i * 16];   // j odd
      }
    }
  };
  auto stage_writes = [&](int buf) {
#pragma unroll
    for (int p = 0; p < 2; ++p) {
      const int pp = wid * 2 + p;
      const int h  = pp >> 4;
      const int k8 = pp & 15;                    // 8-halfword block index
#pragma unroll
      for (int i = 0; i < 4; ++i) {
        const int row = h * 64 + l15 + 16 * i;   // = output col n
        const int kb  = k8 ^ (row & 7);          // XOR swizzle
        h16x2 hp;
        hp[0] = (_Float16)rv[p * 8 + i];
        hp[1] = (_Float16)rv[p * 8 + 4 + i];
        *(unsigned*)&Xt[buf][row * 128 + kb * 8 + 2 * g] = __builtin_bit_cast(unsigned, hp);
      }
    }
  };

  stage_loads(0);                       // T14: global loads in flight during prologue

  // ---- prologue: E1/E2 tables + batch max (log2-scaled domain) ----
  {
    const float v = f2g[b * 1024 + t];
    e1s[t] = fexp2(v);
    e2s[t] = fexp2(ALPHA * v);
    float m = v;
#pragma unroll
    for (int off = 1; off < 64; off <<= 1) m = fmaxf(m, __shfl_xor(m, off));
    if (lane == 0) red[wid] = m;
  }
  const float f1v = f1g[b * 1024 + brow + wr * 16 + l15];
  __syncthreads();   // e1s/e2s/red ready
  float mf2 = red[0];
#pragma unroll
  for (int i = 1; i < 16; ++i) mf2 = fmaxf(mf2, red[i]);
  const float u  = f1v + mf2;
  const float mL = fmaxf(u, ALPHA * u);
  const float CA = fexp2(f1v - mL);
  const float CB = fexp2(fmaf(ALPHA, f1v, -mL));
  stage_writes(0);
  __syncthreads();   // Xt[0] ready

  f32x4 acc[4] = {};
  f32x4 accz = {};
  h16x8 ones;
#pragma unroll
  for (int i = 0; i < 8; ++i) ones[i] = (_Float16)1.0f;

  const int l7 = l15 & 7;

  for (int kc = 0; kc < 8; ++kc) {
    const int buf = kc & 1;
    if (kc < 7) stage_loads(kc + 1);
#pragma unroll
    for (int ks = 0; ks < 4; ++ks) {
      const int jb = kc * 128 + ks * 32 + g * 8;
      f32x4 e1a = *(const f32x4*)(e1s + jb);
      f32x4 e1b = *(const f32x4*)(e1s + jb + 4);
      f32x4 e2a = *(const f32x4*)(e2s + jb);
      f32x4 e2b = *(const f32x4*)(e2s + jb + 4);
      float ev1[8], ev2[8];
#pragma unroll
      for (int i = 0; i < 4; ++i) {
        ev1[i] = e1a[i]; ev1[4 + i] = e1b[i];
        ev2[i] = e2a[i]; ev2[4 + i] = e2b[i];
      }
      h16x8 a0;
#pragma unroll
      for (int jj = 0; jj < 4; ++jj) {
        float p0 = fmaxf(CA * ev1[2 * jj],     CB * ev2[2 * jj]);
        float p1 = fmaxf(CA * ev1[2 * jj + 1], CB * ev2[2 * jj + 1]);
        h16x2 pk = __builtin_bit_cast(h16x2, __builtin_amdgcn_cvt_pkrtz(p0, p1));
        a0[2 * jj] = pk[0]; a0[2 * jj + 1] = pk[1];
      }
#pragma unroll
      for (int nf = 0; nf < 4; ++nf) {
        const int row = wc * 64 + nf * 16 + l15;
        const int kb  = (ks * 4 + g) ^ l7;
        h16x8 bf = *(const h16x8*)&Xt[buf][row * 128 + kb * 8];
        acc[nf] = __builtin_amdgcn_mfma_f32_16x16x32_f16(a0, bf, acc[nf], 0, 0, 0);
      }
      accz = __builtin_amdgcn_mfma_f32_16x16x32_f16(a0, ones, accz, 0, 0, 0);
    }
    if (kc < 7) stage_writes(buf ^ 1);
    __syncthreads();
  }

  // ---- epilogue: Z in accz per-row in-lane; divide and store ----
  float rz[4];
#pragma unroll
  for (int r = 0; r < 4; ++r) rz[r] = 1.0f / accz[r];
  const int i0 = brow + wr * 16;
  const int bo = b + 32 * wc;
  float* op = out + (size_t)bo * 65536;
#pragma unroll
  for (int nf = 0; nf < 4; ++nf) {
    const int n = nf * 16 + l15;          // col within the 64 of this batch-half
#pragma unroll
    for (int r = 0; r < 4; ++r) {
      op[(size_t)(i0 + g * 4 + r) * 64 + n] = acc[nf][r] * rz[r];
    }
  }
}

extern "C" void kernel_launch(void* const* d_in, const int* in_sizes, int n_in,
                              void* d_out, int out_size, void* d_ws, size_t ws_size,
                              hipStream_t stream) {
  const float* emb = (const float*)d_in[0];
  const float* x   = (const float*)d_in[1];
  const float* W   = (const float*)d_in[2];
  const float* a   = (const float*)d_in[3];
  float* f1 = (float*)d_ws;          // 32*1024 floats
  float* f2 = f1 + 32 * 1024;        // 32*1024 floats
  fkern<<<512, 256, 0, stream>>>(emb, W, a, f1, f2);
  attn_main<<<256, 1024, 0, stream>>>(x, f1, f2, (float*)d_out);
}